// Round 1
// baseline (231.532 us; speedup 1.0000x reference)
//
#include <hip/hip_runtime.h>

// Problem constants (MultiHeadAttention_9397388443950)
#define B_   2
#define S_   1024
#define SP_  1024
#define L_   2048      // SP + S
#define E_   2048
#define H_   16
#define HD_  128
#define N3_  6144      // 3*E
#define M_   2048      // B*S
#define SCALE_ 0.08838834764831845f   // 1/sqrt(128)

typedef _Float16 f16x8 __attribute__((ext_vector_type(8)));
typedef _Float16 f16x4 __attribute__((ext_vector_type(4)));
typedef float    f32x4 __attribute__((ext_vector_type(4)));

#define MFMA16(a,b,c) __builtin_amdgcn_mfma_f32_16x16x32_f16(a,b,c,0,0,0)

__device__ __forceinline__ void gload16(const void* g, void* l) {
  __builtin_amdgcn_global_load_lds(
      (const __attribute__((address_space(1))) void*)g,
      (__attribute__((address_space(3))) void*)l, 16, 0, 0);
}

// ---------------- f32 -> fp16 convert (8 elems/thread) ----------------
__global__ __launch_bounds__(256) void k_cvt(const float* __restrict__ in,
                                             _Float16* __restrict__ out, int n8) {
  int t = blockIdx.x * 256 + threadIdx.x;
  if (t >= n8) return;
  const float4* p = (const float4*)in + (size_t)t * 2;
  float4 a = p[0], b = p[1];
  f16x8 o;
  o[0]=(_Float16)a.x; o[1]=(_Float16)a.y; o[2]=(_Float16)a.z; o[3]=(_Float16)a.w;
  o[4]=(_Float16)b.x; o[5]=(_Float16)b.y; o[6]=(_Float16)b.z; o[7]=(_Float16)b.w;
  *((f16x8*)out + t) = o;
}

// ---------------- RoPE cos/sin table: cs[i*128+d] for pos=SP+i -------------
__global__ __launch_bounds__(256) void k_cstab(float2* __restrict__ cs) {
  int t = blockIdx.x * 256 + threadIdx.x;     // 1024*128
  int pos = t >> 7, d = t & 127;
  float inv = exp2f(-(float)(d & 63) * (13.287712379549449f / 64.0f)); // 10000^(-(d&63)/64)
  float ang = (float)(SP_ + pos) * inv;
  float s, c;
  sincosf(ang, &s, &c);
  cs[t] = make_float2(c, s);
}

// ---------------- past_key (B,SP,H,HD) f32 -> Kc (B,H,L,HD) fp16 rows [0,SP) ----
__global__ __launch_bounds__(256) void k_pastk(const float* __restrict__ pk,
                                               _Float16* __restrict__ Kc) {
  int t = blockIdx.x * 256 + threadIdx.x;     // B*H*SP*16
  int d8 = t & 15; int rest = t >> 4;
  int pos = rest & 1023; rest >>= 10;
  int h = rest & 15; int b = rest >> 4;
  const float* src = pk + ((size_t)(b * SP_ + pos) * H_ + h) * HD_ + d8 * 8;
  float4 a = *(const float4*)src, c4 = *(const float4*)(src + 4);
  f16x8 o;
  o[0]=(_Float16)a.x;  o[1]=(_Float16)a.y;  o[2]=(_Float16)a.z;  o[3]=(_Float16)a.w;
  o[4]=(_Float16)c4.x; o[5]=(_Float16)c4.y; o[6]=(_Float16)c4.z; o[7]=(_Float16)c4.w;
  *(f16x8*)(Kc + ((size_t)(b * H_ + h) * L_ + pos) * HD_ + d8 * 8) = o;
}

// ---------------- past_value -> Vt (B,H,HD,L) fp16 cols [0,SP) (transpose) ----
__global__ __launch_bounds__(256) void k_pastv(const float* __restrict__ pv,
                                               _Float16* __restrict__ Vt) {
  __shared__ _Float16 tile[64][72];
  int bh = blockIdx.x; int b = bh >> 4, h = bh & 15;
  int p0 = blockIdx.y * 64, dd0 = blockIdx.z * 64;
  for (int e = threadIdx.x; e < 4096; e += 256) {
    int p = e >> 6, d = e & 63;
    tile[p][d] = (_Float16)pv[((size_t)(b * SP_ + p0 + p) * H_ + h) * HD_ + dd0 + d];
  }
  __syncthreads();
  for (int e = threadIdx.x; e < 4096; e += 256) {
    int d = e >> 6, p = e & 63;
    Vt[((size_t)bh * HD_ + dd0 + d) * L_ + p0 + p] = tile[p][d];
  }
}

// ---------------- new v (from qkvh) -> Vt cols [SP,L) (transpose) ----------
__global__ __launch_bounds__(256) void k_newv(const _Float16* __restrict__ qkvh,
                                              _Float16* __restrict__ Vt) {
  __shared__ _Float16 tile[64][72];
  int bh = blockIdx.x; int b = bh >> 4, h = bh & 15;
  int i0 = blockIdx.y * 64, dd0 = blockIdx.z * 64;
  for (int e = threadIdx.x; e < 4096; e += 256) {
    int p = e >> 6, d = e & 63;
    tile[p][d] = qkvh[(size_t)(b * S_ + i0 + p) * N3_ + 2 * E_ + h * HD_ + dd0 + d];
  }
  __syncthreads();
  for (int e = threadIdx.x; e < 4096; e += 256) {
    int d = e >> 6, p = e & 63;
    Vt[((size_t)bh * HD_ + dd0 + d) * L_ + SP_ + i0 + p] = tile[p][d];
  }
}

// ---------------- RoPE q,k: qkvh -> Qh (scaled) and Kc rows [SP,L) ----------
__global__ __launch_bounds__(256) void k_rope(const _Float16* __restrict__ qkvh,
                                              const float2* __restrict__ cs,
                                              _Float16* __restrict__ Qh,
                                              _Float16* __restrict__ Kc) {
  int t = blockIdx.x * 256 + threadIdx.x;     // M * H * 64 pairs
  int m = t >> 10, pr = t & 1023;
  int h = pr >> 6, dp = pr & 63;
  int d0 = dp * 2;
  int b = m >> 10, i = m & 1023;
  const _Float16* qp = qkvh + (size_t)m * N3_ + h * HD_ + d0;
  float qe = (float)qp[0], qo = (float)qp[1];
  float ke = (float)qp[E_], ko = (float)qp[E_ + 1];
  float2 c0 = cs[i * HD_ + d0], c1 = cs[i * HD_ + d0 + 1];
  // q'[2i] = q[2i]*cos(a0) - q[2i+1]*sin(a0); q'[2i+1] = q[2i+1]*cos(a1) + q[2i]*sin(a1)
  float q0v = qe * c0.x - qo * c0.y;
  float q1v = qo * c1.x + qe * c1.y;
  float k0v = ke * c0.x - ko * c0.y;
  float k1v = ko * c1.x + ke * c1.y;
  size_t qi = ((size_t)(b * H_ + h) * S_ + i) * HD_ + d0;
  Qh[qi]     = (_Float16)(q0v * SCALE_);
  Qh[qi + 1] = (_Float16)(q1v * SCALE_);
  size_t ki = ((size_t)(b * H_ + h) * L_ + SP_ + i) * HD_ + d0;
  Kc[ki]     = (_Float16)k0v;
  Kc[ki + 1] = (_Float16)k1v;
}

// ---------------- GEMM C[m,n] = sum_k A[m,k]*Bw[n,k]  (m97 structure) -------
// 128x128 tile, BK=32, 4 waves (2x2 of 64x64), global_load_lds width 16.
template<bool F16OUT>
__global__ __launch_bounds__(256) void k_gemm(const _Float16* __restrict__ A,
                                              const _Float16* __restrict__ Bw,
                                              void* __restrict__ Cout,
                                              int M, int N, int K) {
  __shared__ _Float16 As[128 * 32];
  __shared__ _Float16 Bs[128 * 32];
  const int tid = threadIdx.x, w = tid >> 6, lane = tid & 63;
  const int r = lane & 15, g = lane >> 4;
  const int m0 = blockIdx.y * 128, n0 = blockIdx.x * 128;
  const int wm = (w >> 1) * 64, wn = (w & 1) * 64;
  f32x4 acc[4][4] = {};
  for (int kt = 0; kt < K; kt += 32) {
#pragma unroll
    for (int it = 0; it < 2; it++) {
      int bg = it * 256 + w * 64;             // wave-uniform base granule
      int gr = bg + lane;                     // per-lane granule (16B)
      int row = gr >> 2, c8 = (gr & 3) * 8;   // 4 granules per 32-elem row
      gload16(A  + (size_t)(m0 + row) * K + kt + c8, &As[bg * 8]);
      gload16(Bw + (size_t)(n0 + row) * K + kt + c8, &Bs[bg * 8]);
    }
    __syncthreads();
    f16x8 af[4], bf[4];
#pragma unroll
    for (int i = 0; i < 4; i++) {
      af[i] = *(const f16x8*)&As[(wm + i * 16 + r) * 32 + g * 8];
      bf[i] = *(const f16x8*)&Bs[(wn + i * 16 + r) * 32 + g * 8];
    }
#pragma unroll
    for (int i = 0; i < 4; i++)
#pragma unroll
      for (int j = 0; j < 4; j++)
        acc[i][j] = MFMA16(af[i], bf[j], acc[i][j]);
    __syncthreads();
  }
#pragma unroll
  for (int i = 0; i < 4; i++)
#pragma unroll
    for (int j = 0; j < 4; j++)
#pragma unroll
      for (int q = 0; q < 4; q++) {
        size_t idx = (size_t)(m0 + wm + i * 16 + g * 4 + q) * N + n0 + wn + j * 16 + r;
        if constexpr (F16OUT) ((_Float16*)Cout)[idx] = (_Float16)acc[i][j][q];
        else                  ((float*)Cout)[idx]    = acc[i][j][q];
      }
}

// ---------------- Flash attention -------------------------------------------
// grid (B*H=32, S/64=16), 4 waves. Each wave: 16 q-rows. KV chunks of 64.
// Swapped QK^T (mfma(K,Q)) -> per-lane q = lane&15, softmax reduce = 2 shfl.
// K LDS [64][128] and Vt LDS [128][64], both XOR-swizzled on 16B granules
// (pre-swizzled global source + linear global_load_lds dest, rule #21).
__global__ __launch_bounds__(256) void k_attn(const _Float16* __restrict__ Qh,
                                              const _Float16* __restrict__ Kc,
                                              const _Float16* __restrict__ Vt,
                                              _Float16* __restrict__ Oh) {
  __shared__ _Float16 Kl[64 * 128];
  __shared__ _Float16 Vl[128 * 64];
  __shared__ _Float16 Pl[4][16 * 64];
  const int tid = threadIdx.x, w = tid >> 6, lane = tid & 63;
  const int r = lane & 15, g = lane >> 4;
  const int bh = blockIdx.x, tile = blockIdx.y;
  const int i0 = tile * 64, q0 = i0 + w * 16;
  const _Float16* Kbase = Kc + (size_t)bh * L_ * HD_;
  const _Float16* Vbase = Vt + (size_t)bh * HD_ * L_;
  // Q fragments (B-operand of swapped QK^T): Q[q0+r][g*8+j+32*kk], pre-scaled
  f16x8 qf[4];
  {
    const _Float16* qp = Qh + ((size_t)bh * S_ + q0 + r) * HD_ + g * 8;
#pragma unroll
    for (int kk = 0; kk < 4; kk++) qf[kk] = *(const f16x8*)(qp + kk * 32);
  }
  f32x4 acc[8] = {};
  float mrun = -1e30f, lrun = 0.f;
  const int lim = SP_ + q0 + r;               // max allowed key pos for my q
  const int nch = (SP_ + i0 + 64) >> 6;
  for (int c = 0; c < nch; c++) {
    const int c0 = c << 6;
    // ---- stage K (64x128) and V^T (128x64), swizzled via permuted source ----
#pragma unroll
    for (int it = 0; it < 4; it++) {
      int bg = it * 256 + w * 64;
      int gr = bg + lane;
      int krow = gr >> 4, kc = ((gr & 15) ^ (krow & 7)) * 8;
      gload16(Kbase + (size_t)(c0 + krow) * HD_ + kc, &Kl[bg * 8]);
      int vrow = gr >> 3, vc = ((gr & 7) ^ (vrow & 7)) * 8;
      gload16(Vbase + (size_t)vrow * L_ + c0 + vc, &Vl[bg * 8]);
    }
    __syncthreads();
    // ---- S^T = K * Q^T : D[key][q], lane holds q=r, keys mf*16+g*4+jj ----
    f32x4 sc[4] = {};
#pragma unroll
    for (int mf = 0; mf < 4; mf++)
#pragma unroll
      for (int kk = 0; kk < 4; kk++) {
        int row = mf * 16 + r;
        int gran = (g + kk * 4) ^ (row & 7);
        f16x8 kf = *(const f16x8*)&Kl[row * 128 + gran * 8];
        sc[mf] = MFMA16(kf, qf[kk], sc[mf]);
      }
    // ---- mask + online softmax (per-lane row q=r) ----
    float p[4][4];
    float rmax = -1e30f;
#pragma unroll
    for (int mf = 0; mf < 4; mf++)
#pragma unroll
      for (int jj = 0; jj < 4; jj++) {
        float v = sc[mf][jj];
        int kp = c0 + mf * 16 + g * 4 + jj;
        if (kp > lim) v = -1e30f;
        p[mf][jj] = v;
        rmax = fmaxf(rmax, v);
      }
    rmax = fmaxf(rmax, __shfl_xor(rmax, 16));
    rmax = fmaxf(rmax, __shfl_xor(rmax, 32));
    float mnew = fmaxf(mrun, rmax);
    float scale = __expf(mrun - mnew);
    float psum = 0.f;
#pragma unroll
    for (int mf = 0; mf < 4; mf++)
#pragma unroll
      for (int jj = 0; jj < 4; jj++) {
        float e = __expf(p[mf][jj] - mnew);
        p[mf][jj] = e;
        psum += e;
      }
    psum += __shfl_xor(psum, 16);
    psum += __shfl_xor(psum, 32);
    lrun = lrun * scale + psum;
    mrun = mnew;
    // ---- P -> per-wave LDS (swizzled), same-wave rd-after-wr (in-order DS) ----
#pragma unroll
    for (int mf = 0; mf < 4; mf++) {
      f16x4 ph;
#pragma unroll
      for (int jj = 0; jj < 4; jj++) ph[jj] = (_Float16)p[mf][jj];
      int g16 = (mf * 2 + (g >> 1)) ^ (r & 7);
      *(f16x4*)&Pl[w][r * 64 + g16 * 8 + (g & 1) * 4] = ph;
    }
    // ---- rescale acc (acc rows are q = g*4+jj; scale lives at lane q) ----
    float scj[4];
#pragma unroll
    for (int jj = 0; jj < 4; jj++) scj[jj] = __shfl(scale, g * 4 + jj);
#pragma unroll
    for (int nf = 0; nf < 8; nf++)
#pragma unroll
      for (int jj = 0; jj < 4; jj++) acc[nf][jj] *= scj[jj];
    // ---- O += P * V : A=P[q][key], B=V[key][d] from transposed Vl ----
#pragma unroll
    for (int kk = 0; kk < 2; kk++) {
      f16x8 pf = *(const f16x8*)&Pl[w][r * 64 + ((g + kk * 4) ^ (r & 7)) * 8];
#pragma unroll
      for (int nf = 0; nf < 8; nf++) {
        int vrow = nf * 16 + r;
        int gran = (g + kk * 4) ^ (vrow & 7);
        f16x8 vf = *(const f16x8*)&Vl[vrow * 64 + gran * 8];
        acc[nf] = MFMA16(pf, vf, acc[nf]);
      }
    }
    __syncthreads();
  }
  // ---- finalize: /l, write Oh[m = b*S+i, e = h*128+d] fp16 ----
  float inv[4];
#pragma unroll
  for (int jj = 0; jj < 4; jj++) inv[jj] = 1.f / __shfl(lrun, g * 4 + jj);
  const int b = bh >> 4, h = bh & 15;
#pragma unroll
  for (int nf = 0; nf < 8; nf++)
#pragma unroll
    for (int jj = 0; jj < 4; jj++) {
      size_t idx = (size_t)(b * S_ + i0 + w * 16 + g * 4 + jj) * E_ + h * HD_ + nf * 16 + r;
      Oh[idx] = (_Float16)(acc[nf][jj] * inv[jj]);
    }
}

extern "C" void kernel_launch(void* const* d_in, const int* in_sizes, int n_in,
                              void* d_out, int out_size, void* d_ws, size_t ws_size,
                              hipStream_t stream) {
  (void)in_sizes; (void)n_in; (void)out_size; (void)ws_size;
  const float* x    = (const float*)d_in[0];
  const float* Wqkv = (const float*)d_in[1];
  const float* Wout = (const float*)d_in[2];
  const float* pk   = (const float*)d_in[3];
  const float* pv   = (const float*)d_in[4];
  // d_in[5]=attn_mask (pure causal, recomputed), d_in[6]=seq_offset (=SP_)

  char* ws = (char*)d_ws;
  _Float16* Xh   = (_Float16*)(ws);               // 8.39MB  (reused as Oh)
  _Float16* Wh   = (_Float16*)(ws + 8388608);     // 25.2MB  (reused as Woh)
  _Float16* qkvh = (_Float16*)(ws + 33554432);    // 25.2MB
  _Float16* Qhb  = (_Float16*)(ws + 58720256);    // 8.39MB
  _Float16* Kcb  = (_Float16*)(ws + 67108864);    // 16.8MB
  _Float16* Vtb  = (_Float16*)(ws + 83886080);    // 16.8MB
  float2*   cs   = (float2*)  (ws + 100663296);   // 1MB    (total ~97MB)
  _Float16* Ohb  = Xh;
  _Float16* Woh  = Wh;

  k_cvt  <<<2048, 256, 0, stream>>>(x, Xh, 524288);
  k_cvt  <<<6144, 256, 0, stream>>>(Wqkv, Wh, 1572864);
  k_cstab<<<512,  256, 0, stream>>>(cs);
  k_pastk<<<2048, 256, 0, stream>>>(pk, Kcb);
  k_pastv<<<dim3(32, 16, 2), 256, 0, stream>>>(pv, Vtb);
  k_gemm<true><<<dim3(48, 16), 256, 0, stream>>>(Xh, Wh, qkvh, M_, N3_, E_);
  k_cvt  <<<2048, 256, 0, stream>>>(Wout, Woh, 524288);     // Wh region free now
  k_rope <<<8192, 256, 0, stream>>>(qkvh, cs, Qhb, Kcb);
  k_newv <<<dim3(32, 16, 2), 256, 0, stream>>>(qkvh, Vtb);
  k_attn <<<dim3(32, 16), 256, 0, stream>>>(Qhb, Kcb, Vtb, Ohb);  // Xh region free
  k_gemm<false><<<dim3(16, 16), 256, 0, stream>>>(Ohb, Woh, d_out, M_, E_, E_);
}